// Round 15
// baseline (439.553 us; speedup 1.0000x reference)
//
#include <hip/hip_runtime.h>
#include <hip/hip_bf16.h>

typedef __attribute__((ext_vector_type(8))) short short8;
typedef __attribute__((ext_vector_type(4))) float f32x4;
typedef unsigned short u16;
typedef unsigned int u32;

#define AS1 __attribute__((address_space(1)))
#define AS3 __attribute__((address_space(3)))

__device__ __forceinline__ void cp16(const void* g, void* l) {
  __builtin_amdgcn_global_load_lds((const AS1 u32*)g, (AS3 u32*)l, 16, 0, 0);
}

__device__ __forceinline__ u16 f2bf(float x) {
  union { float f; unsigned u; } c; c.f = x;
  unsigned u = c.u;
  unsigned r = (u + 0x7fffu + ((u >> 16) & 1u)) >> 16;  // RNE
  return (u16)r;
}

// packed pair cvt: compiler emits v_cvt_pk_bf16_f32
__device__ __forceinline__ u32 pk2bf(float a, float b) {
  __hip_bfloat162 h = __float22bfloat162_rn(float2{a, b});
  union { __hip_bfloat162 h; u32 u; } c; c.h = h; return c.u;
}

__device__ __forceinline__ short8 cvt8(float4 x0, float4 x1) {
  short8 v;
  v[0]=(short)f2bf(x0.x); v[1]=(short)f2bf(x0.y); v[2]=(short)f2bf(x0.z); v[3]=(short)f2bf(x0.w);
  v[4]=(short)f2bf(x1.x); v[5]=(short)f2bf(x1.y); v[6]=(short)f2bf(x1.z); v[7]=(short)f2bf(x1.w);
  return v;
}

// -------- convert fp32 -> bf16: query,key,value -> Xb; Wq,Wk,Wv,Wo -> Wb ----
__global__ __launch_bounds__(256) void cvt_all(
    const float* __restrict__ q, const float* __restrict__ k, const float* __restrict__ v,
    const float* __restrict__ wq, const float* __restrict__ wk,
    const float* __restrict__ wv, const float* __restrict__ wo,
    u16* __restrict__ Xb, u16* __restrict__ Wb)
{
  const int TOT = 3670016;                     // chunks of 8 floats
  for (int c = blockIdx.x * 256 + threadIdx.x; c < TOT; c += gridDim.x * 256) {
    const float* s; u16* d;
    if (c < 3145728) {
      int z = c >> 20, off = c & 1048575;
      s = ((z == 0) ? q : (z == 1) ? k : v) + (size_t)off * 8;
      d = Xb + (size_t)c * 8;
    } else {
      int wc = c - 3145728;
      int z = wc >> 17, off = wc & 131071;
      s = ((z == 0) ? wq : (z == 1) ? wk : (z == 2) ? wv : wo) + (size_t)off * 8;
      d = Wb + (size_t)wc * 8;
    }
    float4 a = ((const float4*)s)[0], b = ((const float4*)s)[1];
    *(short8*)d = cvt8(a, b);
  }
}

// -------- bf16 GEMM core: C(128x128) = A(128xK) * B(128xK)^T, K=1024 --------
template<int SWAP>
__device__ __forceinline__ void gemm_core_bf16(const u16* __restrict__ A,
                                               const u16* __restrict__ B,
                                               u16* As, u16* Bs,
                                               f32x4 acc[4][4])
{
  const int tid = threadIdx.x;
  const int lane = tid & 63, wid = tid >> 6;
  const int lo = lane & 15, hi = lane >> 4;
  const int wr0 = (wid >> 1) * 64, wc0 = (wid & 1) * 64;

  for (int k0 = 0; k0 < 1024; k0 += 64) {
    __syncthreads();
#pragma unroll
    for (int it = 0; it < 4; ++it) {
      int idx = it * 256 + tid;            // 1024 chunks of 16B per matrix
      int row = idx >> 3, slot = idx & 7;
      cp16(A + (size_t)row * 1024 + k0 + slot * 8, As + (size_t)idx * 8);
      cp16(B + (size_t)row * 1024 + k0 + slot * 8, Bs + (size_t)idx * 8);
    }
    __syncthreads();
#pragma unroll
    for (int kk = 0; kk < 2; ++kk) {
      short8 af[4], bfr[4];
      int slot = kk * 4 + hi;
#pragma unroll
      for (int i = 0; i < 4; ++i)
        af[i] = *(const short8*)(&As[(wr0 + i * 16 + lo) * 64 + slot * 8]);
#pragma unroll
      for (int j = 0; j < 4; ++j)
        bfr[j] = *(const short8*)(&Bs[(wc0 + j * 16 + lo) * 64 + slot * 8]);
#pragma unroll
      for (int i = 0; i < 4; ++i)
#pragma unroll
        for (int j = 0; j < 4; ++j)
          acc[i][j] = SWAP
            ? __builtin_amdgcn_mfma_f32_16x16x32_bf16(bfr[j], af[i], acc[i][j], 0, 0, 0)
            : __builtin_amdgcn_mfma_f32_16x16x32_bf16(af[i], bfr[j], acc[i][j], 0, 0, 0);
    }
  }
}

// Flat grid 1536, XCD-chunked (A-tile L2 reuse).
// z=0: Q*0.125*log2e -> Qh[bh][s][d]; z=1: K -> Kh; z=2: V -> Vt[bh][d][s]
__global__ __launch_bounds__(256) void gemm_qkv(
    const u16* __restrict__ Xb, const u16* __restrict__ Wb,
    const float* __restrict__ bq, const float* __restrict__ bk, const float* __restrict__ bv,
    u16* __restrict__ Qh, u16* __restrict__ Kh, u16* __restrict__ Vt)
{
  __shared__ __align__(16) u16 As[128 * 64];
  __shared__ __align__(16) u16 Bs[128 * 64];
  const int bid = blockIdx.x;
  const int w = (bid & 7) * 192 + (bid >> 3);
  const int z = w / 512, r = w % 512;
  const int bm0 = (r >> 3) * 128, bn0 = (r & 7) * 128;
  const u16* A = Xb + (size_t)z * 8388608 + (size_t)bm0 * 1024;
  const u16* W = Wb + (size_t)z * 1048576 + (size_t)bn0 * 1024;
  const float* bias = (z == 0) ? bq : (z == 1) ? bk : bv;

  f32x4 acc[4][4] = {};
  if (z < 2) gemm_core_bf16<0>(A, W, As, Bs, acc);
  else       gemm_core_bf16<1>(A, W, As, Bs, acc);

  const int lane = threadIdx.x & 63, wid = threadIdx.x >> 6;
  const int lo = lane & 15, hi = lane >> 4;
  const int wr0 = (wid >> 1) * 64, wc0 = (wid & 1) * 64;

  if (z < 2) {
    u16* out = (z == 0) ? Qh : Kh;
    // Q carries scale AND log2e so softmax runs in base-2 (exp2 only)
    const float sc = (z == 0) ? 0.125f * 1.44269504088896f : 1.0f;
#pragma unroll
    for (int j = 0; j < 4; ++j) {
      int n = bn0 + wc0 + j * 16 + lo;
      float bb = bias[n];
      int h = n >> 6, d = n & 63;
#pragma unroll
      for (int i = 0; i < 4; ++i)
#pragma unroll
        for (int r2 = 0; r2 < 4; ++r2) {
          int m = bm0 + wr0 + i * 16 + hi * 4 + r2;
          int b = m >> 11, s = m & 2047;
          float v = (acc[i][j][r2] + bb) * sc;
          out[(((size_t)(b * 16 + h)) * 2048 + s) * 64 + d] = f2bf(v);
        }
    }
  } else {
#pragma unroll
    for (int j = 0; j < 4; ++j) {
#pragma unroll
      for (int r2 = 0; r2 < 4; ++r2) {
        int n = bn0 + wc0 + j * 16 + hi * 4 + r2;
        float bb = bias[n];
        int h = n >> 6, d = n & 63;
#pragma unroll
        for (int i = 0; i < 4; ++i) {
          int m = bm0 + wr0 + i * 16 + lo;
          int b = m >> 11, s = m & 2047;
          Vt[(((size_t)(b * 16 + h)) * 64 + d) * 2048 + s] = f2bf(acc[i][j][r2] + bb);
        }
      }
    }
  }
}

__global__ __launch_bounds__(256) void gemm_out(
    const u16* __restrict__ ATT, const u16* __restrict__ Wo,
    const float* __restrict__ bo, float* __restrict__ out)
{
  __shared__ __align__(16) u16 As[128 * 64];
  __shared__ __align__(16) u16 Bs[128 * 64];
  const int bid = blockIdx.x;
  const int w = (bid & 7) * 64 + (bid >> 3);
  const int bm0 = (w >> 3) * 128, bn0 = (w & 7) * 128;
  f32x4 acc[4][4] = {};
  gemm_core_bf16<0>(ATT + (size_t)bm0 * 1024, Wo + (size_t)bn0 * 1024, As, Bs, acc);

  const int lane = threadIdx.x & 63, wid = threadIdx.x >> 6;
  const int lo = lane & 15, hi = lane >> 4;
  const int wr0 = (wid >> 1) * 64, wc0 = (wid & 1) * 64;
#pragma unroll
  for (int j = 0; j < 4; ++j) {
    int n = bn0 + wc0 + j * 16 + lo;
    float bb = bo[n];
#pragma unroll
    for (int i = 0; i < 4; ++i)
#pragma unroll
      for (int r = 0; r < 4; ++r) {
        int m = bm0 + wr0 + i * 16 + hi * 4 + r;
        out[(size_t)m * 1024 + n] = acc[i][j][r] + bb;
      }
  }
}

// -------- fused attention: T14 async-STAGE + T12 permlane P-redistribute ---
// Block = 64 q-rows of one (b,h); 4 waves x 16 q. KVBLK=64. Base-2 softmax.
// P's C-layout (q=lo, t=j*16+hi*4+r) -> PV A-layout (q=lo, t=c*32+hi*8+e)
// moves data only between equal-lo lanes: permlane32_swap + permlane16_swap
// (VALU) replace the Ps LDS round-trip entirely. LDS 40->32 KB (5 blk/CU).
// T5: setprio(1) around MFMA clusters.
#define C2 11.5415603f   /* 8 * log2(e) */
__global__ __launch_bounds__(256) void attn_fused(
    const u16* __restrict__ Qh, const u16* __restrict__ Kh,
    const u16* __restrict__ Vt, float* __restrict__ attnOut,
    u16* __restrict__ ATT)
{
  __shared__ __align__(16) u16 Ks[2][64 * 64];
  __shared__ __align__(16) u16 Vs[2][64 * 64];
  const int tid = threadIdx.x, lane = tid & 63, wid = tid >> 6;
  const int lo = lane & 15, hi = lane >> 4;
  // XCD swizzle: XCD i owns bh in [i*8, i*8+8)
  const int bid = blockIdx.x;
  const int xcd = bid & 7, idx = bid >> 3;
  const int bh = xcd * 8 + (idx >> 5);
  const int q0 = (idx & 31) * 64;
  const int wq0 = wid * 16;
  const int qr = wq0 + lo;

  const u16* Qg  = Qh + ((size_t)bh * 2048 + q0) * 64;
  const u16* Kg0 = Kh + (size_t)bh * 2048 * 64;
  const u16* Vg0 = Vt + (size_t)bh * 64 * 2048;

  // staging map: thread covers i2 in {tid, 256+tid} -> (row, slot)
  const int srow0 = tid >> 3,         sslot0 = tid & 7;
  const int srow1 = (256 + tid) >> 3, sslot1 = tid & 7;
  const int dst0 = srow0 * 64 + ((sslot0 ^ (srow0 & 7)) << 3);
  const int dst1 = srow1 * 64 + ((sslot1 ^ (srow1 & 7)) << 3);

  short8 qa[2];
#pragma unroll
  for (int kk = 0; kk < 2; ++kk)
    qa[kk] = *(const short8*)(Qg + qr * 64 + (kk * 4 + hi) * 8);

  // ---- pass 1: lsum = sum 2^(sc - C2); K reg-dbuf, 1 barrier/tile ----
  {
    short8 k0 = *(const short8*)(Kg0 + (size_t)srow0 * 64 + sslot0 * 8);
    short8 k1 = *(const short8*)(Kg0 + (size_t)srow1 * 64 + sslot1 * 8);
    *(short8*)(&Ks[0][dst0]) = k0;
    *(short8*)(&Ks[0][dst1]) = k1;
  }
  __syncthreads();
  float lsum = 0.f;
  for (int kt = 0; kt < 32; ++kt) {
    const int cur = kt & 1;
    short8 kn0, kn1;
    if (kt < 31) {
      const u16* Kn = Kg0 + (size_t)(kt + 1) * 4096;
      kn0 = *(const short8*)(Kn + (size_t)srow0 * 64 + sslot0 * 8);
      kn1 = *(const short8*)(Kn + (size_t)srow1 * 64 + sslot1 * 8);
    }
    f32x4 sc[4] = {};
    __builtin_amdgcn_s_setprio(1);
#pragma unroll
    for (int kk = 0; kk < 2; ++kk) {
      int slot = kk * 4 + hi;
#pragma unroll
      for (int j = 0; j < 4; ++j) {
        int row = j * 16 + lo;
        short8 kb = *(const short8*)(&Ks[cur][row * 64 + ((slot ^ (row & 7)) << 3)]);
        sc[j] = __builtin_amdgcn_mfma_f32_16x16x32_bf16(kb, qa[kk], sc[j], 0, 0, 0);
      }
    }
    __builtin_amdgcn_s_setprio(0);
#pragma unroll
    for (int j = 0; j < 4; ++j)
#pragma unroll
      for (int r = 0; r < 4; ++r) lsum += __builtin_amdgcn_exp2f(sc[j][r] - C2);
    if (kt < 31) {
      *(short8*)(&Ks[cur ^ 1][dst0]) = kn0;
      *(short8*)(&Ks[cur ^ 1][dst1]) = kn1;
    }
    __syncthreads();
  }
  lsum += __shfl_xor(lsum, 16);
  lsum += __shfl_xor(lsum, 32);
  const float shift2 = C2 + __builtin_amdgcn_logf(lsum);   // p = 2^(sc - shift2)

  // ---- pass 2: K+V reg-dbuf, 1 barrier/tile, permlane P-redistribute ----
  {
    short8 k0 = *(const short8*)(Kg0 + (size_t)srow0 * 64 + sslot0 * 8);
    short8 k1 = *(const short8*)(Kg0 + (size_t)srow1 * 64 + sslot1 * 8);
    short8 v0 = *(const short8*)(Vg0 + (size_t)srow0 * 2048 + sslot0 * 8);
    short8 v1 = *(const short8*)(Vg0 + (size_t)srow1 * 2048 + sslot1 * 8);
    *(short8*)(&Ks[0][dst0]) = k0;  *(short8*)(&Ks[0][dst1]) = k1;
    *(short8*)(&Vs[0][dst0]) = v0;  *(short8*)(&Vs[0][dst1]) = v1;
  }
  __syncthreads();
  f32x4 oacc[4] = {};
  for (int kt = 0; kt < 32; ++kt) {
    const int cur = kt & 1;
    const int t0 = kt * 64;
    // (1) issue next-tile loads into registers (not drained by s_barrier)
    short8 kn0, kn1, vn0, vn1;
    if (kt < 31) {
      const u16* Kn = Kg0 + (size_t)(kt + 1) * 4096;
      kn0 = *(const short8*)(Kn + (size_t)srow0 * 64 + sslot0 * 8);
      kn1 = *(const short8*)(Kn + (size_t)srow1 * 64 + sslot1 * 8);
      vn0 = *(const short8*)(Vg0 + (size_t)srow0 * 2048 + (t0 + 64) + sslot0 * 8);
      vn1 = *(const short8*)(Vg0 + (size_t)srow1 * 2048 + (t0 + 64) + sslot1 * 8);
    }
    // (2) compute current tile
    f32x4 sc[4] = {};
    __builtin_amdgcn_s_setprio(1);
#pragma unroll
    for (int kk = 0; kk < 2; ++kk) {
      int slot = kk * 4 + hi;
#pragma unroll
      for (int j = 0; j < 4; ++j) {
        int row = j * 16 + lo;
        short8 kb = *(const short8*)(&Ks[cur][row * 64 + ((slot ^ (row & 7)) << 3)]);
        sc[j] = __builtin_amdgcn_mfma_f32_16x16x32_bf16(kb, qa[kk], sc[j], 0, 0, 0);
      }
    }
    __builtin_amdgcn_s_setprio(0);
    float p[4][4];
#pragma unroll
    for (int j = 0; j < 4; ++j)
#pragma unroll
      for (int r = 0; r < 4; ++r) p[j][r] = __builtin_amdgcn_exp2f(sc[j][r] - shift2);

    float* aOut = attnOut + ((size_t)bh * 2048 + q0 + qr) * 2048 + t0 + hi * 4;
#pragma unroll
    for (int j = 0; j < 4; ++j) {
      f32x4 f4;
      f4[0] = p[j][0]; f4[1] = p[j][1]; f4[2] = p[j][2]; f4[3] = p[j][3];
      __builtin_nontemporal_store(f4, (f32x4*)(aOut + j * 16));
    }
    // T12: P C-layout -> A-layout via permlane (equal-lo lanes only, no LDS).
    // U,V = pk(p[2c][01]), pk(p[2c+1][01]); S,T = pk(p[2c][23]), pk(p[2c+1][23])
    // permlane32_swap(U,V); permlane16_swap(U,V) => U=w0(e0,1), V=w2(e4,5)
    // same on (S,T) => S=w1(e2,3), T=w3(e6,7).
    u32 w01[4], w23[4];
#pragma unroll
    for (int j = 0; j < 4; ++j) {
      w01[j] = pk2bf(p[j][0], p[j][1]);
      w23[j] = pk2bf(p[j][2], p[j][3]);
    }
#pragma unroll
    for (int c = 0; c < 2; ++c) {
      u32 U = w01[c * 2], V = w01[c * 2 + 1];
      u32 S = w23[c * 2], T = w23[c * 2 + 1];
      asm volatile("v_permlane32_swap_b32 %0, %1" : "+v"(U), "+v"(V));
      asm volatile("v_permlane16_swap_b32 %0, %1" : "+v"(U), "+v"(V));
      asm volatile("v_permlane32_swap_b32 %0, %1" : "+v"(S), "+v"(T));
      asm volatile("v_permlane16_swap_b32 %0, %1" : "+v"(S), "+v"(T));
      short8 pa;
      ((u32*)&pa)[0] = U; ((u32*)&pa)[1] = S;
      ((u32*)&pa)[2] = V; ((u32*)&pa)[3] = T;
      int slot = c * 4 + hi;
      __builtin_amdgcn_s_setprio(1);
#pragma unroll
      for (int j4 = 0; j4 < 4; ++j4) {
        int vrow = j4 * 16 + lo;
        short8 vb = *(const short8*)(&Vs[cur][vrow * 64 + ((slot ^ (vrow & 7)) << 3)]);
        oacc[j4] = __builtin_amdgcn_mfma_f32_16x16x32_bf16(pa, vb, oacc[j4], 0, 0, 0);
      }
      __builtin_amdgcn_s_setprio(0);
    }
    // (3) write-late: landed regs -> alternate buffer, then ONE barrier
    if (kt < 31) {
      *(short8*)(&Ks[cur ^ 1][dst0]) = kn0;
      *(short8*)(&Ks[cur ^ 1][dst1]) = kn1;
      *(short8*)(&Vs[cur ^ 1][dst0]) = vn0;
      *(short8*)(&Vs[cur ^ 1][dst1]) = vn1;
    }
    __syncthreads();
  }
  // attended -> ATT[b*2048+q][h*64+d] bf16 (col=lo -> d, row=hi*4+r -> q)
  const int b = bh >> 4, h = bh & 15;
#pragma unroll
  for (int j = 0; j < 4; ++j)
#pragma unroll
    for (int r = 0; r < 4; ++r) {
      int ql = wq0 + hi * 4 + r;
      int d = j * 16 + lo;
      size_t row = (size_t)b * 2048 + q0 + ql;
      ATT[row * 1024 + h * 64 + d] = f2bf(oacc[j][r]);
    }
}

extern "C" void kernel_launch(void* const* d_in, const int* in_sizes, int n_in,
                              void* d_out, int out_size, void* d_ws, size_t ws_size,
                              hipStream_t stream) {
  const float* query = (const float*)d_in[0];
  const float* key   = (const float*)d_in[1];
  const float* value = (const float*)d_in[2];
  const float* Wq = (const float*)d_in[3];
  const float* bq = (const float*)d_in[4];
  const float* Wk = (const float*)d_in[5];
  const float* bk = (const float*)d_in[6];
  const float* Wv = (const float*)d_in[7];
  const float* bv = (const float*)d_in[8];
  const float* Wo = (const float*)d_in[9];
  const float* bo = (const float*)d_in[10];

  // ws layout (u16 units):
  u16* Xb  = (u16*)d_ws;               // 25165824 (q|k|v bf16)
  u16* Wb  = Xb + 25165824;            // 4194304  (Wq|Wk|Wv|Wo bf16)
  u16* Qh  = Wb + 4194304;             // 8388608
  u16* Kh  = Qh + 8388608;             // 8388608
  u16* Vt  = Kh + 8388608;             // 8388608   (total ~109 MB)
  u16* ATT = Xb;                        // alias Xb (dead after gemm_qkv)

  float* outO  = (float*)d_out;
  float* attnO = outO + (size_t)8388608;

  cvt_all<<<2048, 256, 0, stream>>>(query, key, value, Wq, Wk, Wv, Wo, Xb, Wb);
  gemm_qkv<<<1536, 256, 0, stream>>>(Xb, Wb, bq, bk, bv, Qh, Kh, Vt);
  attn_fused<<<2048, 256, 0, stream>>>(Qh, Kh, Vt, attnO, ATT);
  gemm_out<<<512, 256, 0, stream>>>(ATT, Wb + 3145728, bo, outO);
}

// Round 16
// 379.011 us; speedup vs baseline: 1.1597x; 1.1597x over previous
//
#include <hip/hip_runtime.h>
#include <hip/hip_bf16.h>

typedef __attribute__((ext_vector_type(8))) short short8;
typedef __attribute__((ext_vector_type(4))) float f32x4;
typedef unsigned short u16;
typedef unsigned int u32;

#define AS1 __attribute__((address_space(1)))
#define AS3 __attribute__((address_space(3)))

__device__ __forceinline__ void cp16(const void* g, void* l) {
  __builtin_amdgcn_global_load_lds((const AS1 u32*)g, (AS3 u32*)l, 16, 0, 0);
}

__device__ __forceinline__ u16 f2bf(float x) {
  union { float f; unsigned u; } c; c.f = x;
  unsigned u = c.u;
  unsigned r = (u + 0x7fffu + ((u >> 16) & 1u)) >> 16;  // RNE
  return (u16)r;
}

// packed pair cvt: compiler emits v_cvt_pk_bf16_f32
__device__ __forceinline__ u32 pk2bf(float a, float b) {
  __hip_bfloat162 h = __float22bfloat162_rn(float2{a, b});
  union { __hip_bfloat162 h; u32 u; } c; c.h = h; return c.u;
}

__device__ __forceinline__ short8 cvt8(float4 x0, float4 x1) {
  short8 v;
  v[0]=(short)f2bf(x0.x); v[1]=(short)f2bf(x0.y); v[2]=(short)f2bf(x0.z); v[3]=(short)f2bf(x0.w);
  v[4]=(short)f2bf(x1.x); v[5]=(short)f2bf(x1.y); v[6]=(short)f2bf(x1.z); v[7]=(short)f2bf(x1.w);
  return v;
}

// -------- convert fp32 -> bf16: query,key,value -> Xb; Wq,Wk,Wv,Wo -> Wb ----
__global__ __launch_bounds__(256) void cvt_all(
    const float* __restrict__ q, const float* __restrict__ k, const float* __restrict__ v,
    const float* __restrict__ wq, const float* __restrict__ wk,
    const float* __restrict__ wv, const float* __restrict__ wo,
    u16* __restrict__ Xb, u16* __restrict__ Wb)
{
  const int TOT = 3670016;                     // chunks of 8 floats
  for (int c = blockIdx.x * 256 + threadIdx.x; c < TOT; c += gridDim.x * 256) {
    const float* s; u16* d;
    if (c < 3145728) {
      int z = c >> 20, off = c & 1048575;
      s = ((z == 0) ? q : (z == 1) ? k : v) + (size_t)off * 8;
      d = Xb + (size_t)c * 8;
    } else {
      int wc = c - 3145728;
      int z = wc >> 17, off = wc & 131071;
      s = ((z == 0) ? wq : (z == 1) ? wk : (z == 2) ? wv : wo) + (size_t)off * 8;
      d = Wb + (size_t)wc * 8;
    }
    float4 a = ((const float4*)s)[0], b = ((const float4*)s)[1];
    *(short8*)d = cvt8(a, b);
  }
}

// -------- bf16 GEMM core: C(128x128) = A(128xK) * B(128xK)^T, K=1024 --------
template<int SWAP>
__device__ __forceinline__ void gemm_core_bf16(const u16* __restrict__ A,
                                               const u16* __restrict__ B,
                                               u16* As, u16* Bs,
                                               f32x4 acc[4][4])
{
  const int tid = threadIdx.x;
  const int lane = tid & 63, wid = tid >> 6;
  const int lo = lane & 15, hi = lane >> 4;
  const int wr0 = (wid >> 1) * 64, wc0 = (wid & 1) * 64;

  for (int k0 = 0; k0 < 1024; k0 += 64) {
    __syncthreads();
#pragma unroll
    for (int it = 0; it < 4; ++it) {
      int idx = it * 256 + tid;            // 1024 chunks of 16B per matrix
      int row = idx >> 3, slot = idx & 7;
      cp16(A + (size_t)row * 1024 + k0 + slot * 8, As + (size_t)idx * 8);
      cp16(B + (size_t)row * 1024 + k0 + slot * 8, Bs + (size_t)idx * 8);
    }
    __syncthreads();
#pragma unroll
    for (int kk = 0; kk < 2; ++kk) {
      short8 af[4], bfr[4];
      int slot = kk * 4 + hi;
#pragma unroll
      for (int i = 0; i < 4; ++i)
        af[i] = *(const short8*)(&As[(wr0 + i * 16 + lo) * 64 + slot * 8]);
#pragma unroll
      for (int j = 0; j < 4; ++j)
        bfr[j] = *(const short8*)(&Bs[(wc0 + j * 16 + lo) * 64 + slot * 8]);
#pragma unroll
      for (int i = 0; i < 4; ++i)
#pragma unroll
        for (int j = 0; j < 4; ++j)
          acc[i][j] = SWAP
            ? __builtin_amdgcn_mfma_f32_16x16x32_bf16(bfr[j], af[i], acc[i][j], 0, 0, 0)
            : __builtin_amdgcn_mfma_f32_16x16x32_bf16(af[i], bfr[j], acc[i][j], 0, 0, 0);
    }
  }
}

// Flat grid 1536, XCD-chunked (A-tile L2 reuse).
// z=0: Q*0.125*log2e -> Qh[bh][s][d]; z=1: K -> Kh; z=2: V -> Vt[bh][d][s]
__global__ __launch_bounds__(256) void gemm_qkv(
    const u16* __restrict__ Xb, const u16* __restrict__ Wb,
    const float* __restrict__ bq, const float* __restrict__ bk, const float* __restrict__ bv,
    u16* __restrict__ Qh, u16* __restrict__ Kh, u16* __restrict__ Vt)
{
  __shared__ __align__(16) u16 As[128 * 64];
  __shared__ __align__(16) u16 Bs[128 * 64];
  const int bid = blockIdx.x;
  const int w = (bid & 7) * 192 + (bid >> 3);
  const int z = w / 512, r = w % 512;
  const int bm0 = (r >> 3) * 128, bn0 = (r & 7) * 128;
  const u16* A = Xb + (size_t)z * 8388608 + (size_t)bm0 * 1024;
  const u16* W = Wb + (size_t)z * 1048576 + (size_t)bn0 * 1024;
  const float* bias = (z == 0) ? bq : (z == 1) ? bk : bv;

  f32x4 acc[4][4] = {};
  if (z < 2) gemm_core_bf16<0>(A, W, As, Bs, acc);
  else       gemm_core_bf16<1>(A, W, As, Bs, acc);

  const int lane = threadIdx.x & 63, wid = threadIdx.x >> 6;
  const int lo = lane & 15, hi = lane >> 4;
  const int wr0 = (wid >> 1) * 64, wc0 = (wid & 1) * 64;

  if (z < 2) {
    u16* out = (z == 0) ? Qh : Kh;
    // Q carries scale AND log2e so softmax runs in base-2 (exp2 only)
    const float sc = (z == 0) ? 0.125f * 1.44269504088896f : 1.0f;
#pragma unroll
    for (int j = 0; j < 4; ++j) {
      int n = bn0 + wc0 + j * 16 + lo;
      float bb = bias[n];
      int h = n >> 6, d = n & 63;
#pragma unroll
      for (int i = 0; i < 4; ++i)
#pragma unroll
        for (int r2 = 0; r2 < 4; ++r2) {
          int m = bm0 + wr0 + i * 16 + hi * 4 + r2;
          int b = m >> 11, s = m & 2047;
          float v = (acc[i][j][r2] + bb) * sc;
          out[(((size_t)(b * 16 + h)) * 2048 + s) * 64 + d] = f2bf(v);
        }
    }
  } else {
#pragma unroll
    for (int j = 0; j < 4; ++j) {
#pragma unroll
      for (int r2 = 0; r2 < 4; ++r2) {
        int n = bn0 + wc0 + j * 16 + hi * 4 + r2;
        float bb = bias[n];
        int h = n >> 6, d = n & 63;
#pragma unroll
        for (int i = 0; i < 4; ++i) {
          int m = bm0 + wr0 + i * 16 + lo;
          int b = m >> 11, s = m & 2047;
          Vt[(((size_t)(b * 16 + h)) * 64 + d) * 2048 + s] = f2bf(acc[i][j][r2] + bb);
        }
      }
    }
  }
}

__global__ __launch_bounds__(256) void gemm_out(
    const u16* __restrict__ ATT, const u16* __restrict__ Wo,
    const float* __restrict__ bo, float* __restrict__ out)
{
  __shared__ __align__(16) u16 As[128 * 64];
  __shared__ __align__(16) u16 Bs[128 * 64];
  const int bid = blockIdx.x;
  const int w = (bid & 7) * 64 + (bid >> 3);
  const int bm0 = (w >> 3) * 128, bn0 = (w & 7) * 128;
  f32x4 acc[4][4] = {};
  gemm_core_bf16<0>(ATT + (size_t)bm0 * 1024, Wo + (size_t)bn0 * 1024, As, Bs, acc);

  const int lane = threadIdx.x & 63, wid = threadIdx.x >> 6;
  const int lo = lane & 15, hi = lane >> 4;
  const int wr0 = (wid >> 1) * 64, wc0 = (wid & 1) * 64;
#pragma unroll
  for (int j = 0; j < 4; ++j) {
    int n = bn0 + wc0 + j * 16 + lo;
    float bb = bo[n];
#pragma unroll
    for (int i = 0; i < 4; ++i)
#pragma unroll
      for (int r = 0; r < 4; ++r) {
        int m = bm0 + wr0 + i * 16 + hi * 4 + r;
        out[(size_t)m * 1024 + n] = acc[i][j][r] + bb;
      }
  }
}

// -------- fused attention: T14 async-STAGE + permlane PV + coalesced store -
// Block = 64 q-rows of one (b,h); 4 waves x 16 q. KVBLK=64. Base-2 softmax.
// NEW: attn stores routed through a wave-private 2KB LDS transpose (two 32-t
// halves, XOR swizzle, no barriers - per-wave DS ops are in-order) so each
// NT store instruction writes 8 rows x 128B contiguous (was 16 rows x 64B).
#define C2 11.5415603f   /* 8 * log2(e) */
__global__ __launch_bounds__(256) void attn_fused(
    const u16* __restrict__ Qh, const u16* __restrict__ Kh,
    const u16* __restrict__ Vt, float* __restrict__ attnOut,
    u16* __restrict__ ATT)
{
  __shared__ __align__(16) u16 Ks[2][64 * 64];
  __shared__ __align__(16) u16 Vs[2][64 * 64];
  __shared__ __align__(16) float Tb[4 * 512];   // 8 KB: per-wave 16q x 32t f32
  const int tid = threadIdx.x, lane = tid & 63, wid = tid >> 6;
  const int lo = lane & 15, hi = lane >> 4;
  // XCD swizzle: XCD i owns bh in [i*8, i*8+8)
  const int bid = blockIdx.x;
  const int xcd = bid & 7, idx = bid >> 3;
  const int bh = xcd * 8 + (idx >> 5);
  const int q0 = (idx & 31) * 64;
  const int wq0 = wid * 16;
  const int qr = wq0 + lo;

  const u16* Qg  = Qh + ((size_t)bh * 2048 + q0) * 64;
  const u16* Kg0 = Kh + (size_t)bh * 2048 * 64;
  const u16* Vg0 = Vt + (size_t)bh * 64 * 2048;
  char* Twc = (char*)Tb + wid * 2048;           // this wave's 2 KB slice

  // staging map: thread covers i2 in {tid, 256+tid} -> (row, slot)
  const int srow0 = tid >> 3,         sslot0 = tid & 7;
  const int srow1 = (256 + tid) >> 3, sslot1 = tid & 7;
  const int dst0 = srow0 * 64 + ((sslot0 ^ (srow0 & 7)) << 3);
  const int dst1 = srow1 * 64 + ((sslot1 ^ (srow1 & 7)) << 3);

  short8 qa[2];
#pragma unroll
  for (int kk = 0; kk < 2; ++kk)
    qa[kk] = *(const short8*)(Qg + qr * 64 + (kk * 4 + hi) * 8);

  // ---- pass 1: lsum = sum 2^(sc - C2); K reg-dbuf, 1 barrier/tile ----
  {
    short8 k0 = *(const short8*)(Kg0 + (size_t)srow0 * 64 + sslot0 * 8);
    short8 k1 = *(const short8*)(Kg0 + (size_t)srow1 * 64 + sslot1 * 8);
    *(short8*)(&Ks[0][dst0]) = k0;
    *(short8*)(&Ks[0][dst1]) = k1;
  }
  __syncthreads();
  float lsum = 0.f;
  for (int kt = 0; kt < 32; ++kt) {
    const int cur = kt & 1;
    short8 kn0, kn1;
    if (kt < 31) {
      const u16* Kn = Kg0 + (size_t)(kt + 1) * 4096;
      kn0 = *(const short8*)(Kn + (size_t)srow0 * 64 + sslot0 * 8);
      kn1 = *(const short8*)(Kn + (size_t)srow1 * 64 + sslot1 * 8);
    }
    f32x4 sc[4] = {};
    __builtin_amdgcn_s_setprio(1);
#pragma unroll
    for (int kk = 0; kk < 2; ++kk) {
      int slot = kk * 4 + hi;
#pragma unroll
      for (int j = 0; j < 4; ++j) {
        int row = j * 16 + lo;
        short8 kb = *(const short8*)(&Ks[cur][row * 64 + ((slot ^ (row & 7)) << 3)]);
        sc[j] = __builtin_amdgcn_mfma_f32_16x16x32_bf16(kb, qa[kk], sc[j], 0, 0, 0);
      }
    }
    __builtin_amdgcn_s_setprio(0);
#pragma unroll
    for (int j = 0; j < 4; ++j)
#pragma unroll
      for (int r = 0; r < 4; ++r) lsum += __builtin_amdgcn_exp2f(sc[j][r] - C2);
    if (kt < 31) {
      *(short8*)(&Ks[cur ^ 1][dst0]) = kn0;
      *(short8*)(&Ks[cur ^ 1][dst1]) = kn1;
    }
    __syncthreads();
  }
  lsum += __shfl_xor(lsum, 16);
  lsum += __shfl_xor(lsum, 32);
  const float shift2 = C2 + __builtin_amdgcn_logf(lsum);   // p = 2^(sc - shift2)

  // ---- pass 2: K+V reg-dbuf, 1 barrier/tile, permlane PV, coalesced store -
  {
    short8 k0 = *(const short8*)(Kg0 + (size_t)srow0 * 64 + sslot0 * 8);
    short8 k1 = *(const short8*)(Kg0 + (size_t)srow1 * 64 + sslot1 * 8);
    short8 v0 = *(const short8*)(Vg0 + (size_t)srow0 * 2048 + sslot0 * 8);
    short8 v1 = *(const short8*)(Vg0 + (size_t)srow1 * 2048 + sslot1 * 8);
    *(short8*)(&Ks[0][dst0]) = k0;  *(short8*)(&Ks[0][dst1]) = k1;
    *(short8*)(&Vs[0][dst0]) = v0;  *(short8*)(&Vs[0][dst1]) = v1;
  }
  __syncthreads();
  f32x4 oacc[4] = {};
  for (int kt = 0; kt < 32; ++kt) {
    const int cur = kt & 1;
    const int t0 = kt * 64;
    // (1) issue next-tile loads into registers (not drained by s_barrier)
    short8 kn0, kn1, vn0, vn1;
    if (kt < 31) {
      const u16* Kn = Kg0 + (size_t)(kt + 1) * 4096;
      kn0 = *(const short8*)(Kn + (size_t)srow0 * 64 + sslot0 * 8);
      kn1 = *(const short8*)(Kn + (size_t)srow1 * 64 + sslot1 * 8);
      vn0 = *(const short8*)(Vg0 + (size_t)srow0 * 2048 + (t0 + 64) + sslot0 * 8);
      vn1 = *(const short8*)(Vg0 + (size_t)srow1 * 2048 + (t0 + 64) + sslot1 * 8);
    }
    // (2) compute current tile
    f32x4 sc[4] = {};
    __builtin_amdgcn_s_setprio(1);
#pragma unroll
    for (int kk = 0; kk < 2; ++kk) {
      int slot = kk * 4 + hi;
#pragma unroll
      for (int j = 0; j < 4; ++j) {
        int row = j * 16 + lo;
        short8 kb = *(const short8*)(&Ks[cur][row * 64 + ((slot ^ (row & 7)) << 3)]);
        sc[j] = __builtin_amdgcn_mfma_f32_16x16x32_bf16(kb, qa[kk], sc[j], 0, 0, 0);
      }
    }
    __builtin_amdgcn_s_setprio(0);
    float p[4][4];
#pragma unroll
    for (int j = 0; j < 4; ++j)
#pragma unroll
      for (int r = 0; r < 4; ++r) p[j][r] = __builtin_amdgcn_exp2f(sc[j][r] - shift2);

    // T12: P C-layout -> A-layout via permlane (equal-lo lanes only, no LDS).
    u32 w01[4], w23[4];
#pragma unroll
    for (int j = 0; j < 4; ++j) {
      w01[j] = pk2bf(p[j][0], p[j][1]);
      w23[j] = pk2bf(p[j][2], p[j][3]);
    }
#pragma unroll
    for (int c = 0; c < 2; ++c) {
      u32 U = w01[c * 2], V = w01[c * 2 + 1];
      u32 S = w23[c * 2], T = w23[c * 2 + 1];
      asm volatile("v_permlane32_swap_b32 %0, %1" : "+v"(U), "+v"(V));
      asm volatile("v_permlane16_swap_b32 %0, %1" : "+v"(U), "+v"(V));
      asm volatile("v_permlane32_swap_b32 %0, %1" : "+v"(S), "+v"(T));
      asm volatile("v_permlane16_swap_b32 %0, %1" : "+v"(S), "+v"(T));
      short8 pa;
      ((u32*)&pa)[0] = U; ((u32*)&pa)[1] = S;
      ((u32*)&pa)[2] = V; ((u32*)&pa)[3] = T;
      int slot = c * 4 + hi;
      __builtin_amdgcn_s_setprio(1);
#pragma unroll
      for (int j4 = 0; j4 < 4; ++j4) {
        int vrow = j4 * 16 + lo;
        short8 vb = *(const short8*)(&Vs[cur][vrow * 64 + ((slot ^ (vrow & 7)) << 3)]);
        oacc[j4] = __builtin_amdgcn_mfma_f32_16x16x32_bf16(pa, vb, oacc[j4], 0, 0, 0);
      }
      __builtin_amdgcn_s_setprio(0);
    }
    // coalesced attn store: per-wave LDS transpose, two 32-t halves.
    // Write: lane (lo,hi) puts p[c*2+j2][0..3] at row=lo, tl=j2*16+hi*4.
    // Read: lane n -> row=i2*8+(n>>3), chunk=n&7 -> 8 rows x 128B contiguous
    // per store instruction. Wave-private; DS ops in-order within a wave.
#pragma unroll
    for (int c = 0; c < 2; ++c) {
#pragma unroll
      for (int j2 = 0; j2 < 2; ++j2) {
        int j = c * 2 + j2;
        f32x4 f4;
        f4[0] = p[j][0]; f4[1] = p[j][1]; f4[2] = p[j][2]; f4[3] = p[j][3];
        int byte = (lo * 128 + j2 * 64 + hi * 16) ^ ((lo & 7) << 4);
        *(f32x4*)(Twc + byte) = f4;
      }
#pragma unroll
      for (int i2 = 0; i2 < 2; ++i2) {
        int row = i2 * 8 + (lane >> 3), chunk = lane & 7;
        int byte = (row * 128 + chunk * 16) ^ ((row & 7) << 4);
        f32x4 v = *(const f32x4*)(Twc + byte);
        __builtin_nontemporal_store(v,
          (f32x4*)(attnOut + ((size_t)bh * 2048 + q0 + wq0 + row) * 2048
                   + t0 + c * 32 + chunk * 4));
      }
    }
    // (3) write-late: landed regs -> alternate buffer, then ONE barrier
    if (kt < 31) {
      *(short8*)(&Ks[cur ^ 1][dst0]) = kn0;
      *(short8*)(&Ks[cur ^ 1][dst1]) = kn1;
      *(short8*)(&Vs[cur ^ 1][dst0]) = vn0;
      *(short8*)(&Vs[cur ^ 1][dst1]) = vn1;
    }
    __syncthreads();
  }
  // attended -> ATT[b*2048+q][h*64+d] bf16 (col=lo -> d, row=hi*4+r -> q)
  const int b = bh >> 4, h = bh & 15;
#pragma unroll
  for (int j = 0; j < 4; ++j)
#pragma unroll
    for (int r = 0; r < 4; ++r) {
      int ql = wq0 + hi * 4 + r;
      int d = j * 16 + lo;
      size_t row = (size_t)b * 2048 + q0 + ql;
      ATT[row * 1024 + h * 64 + d] = f2bf(oacc[j][r]);
    }
}

extern "C" void kernel_launch(void* const* d_in, const int* in_sizes, int n_in,
                              void* d_out, int out_size, void* d_ws, size_t ws_size,
                              hipStream_t stream) {
  const float* query = (const float*)d_in[0];
  const float* key   = (const float*)d_in[1];
  const float* value = (const float*)d_in[2];
  const float* Wq = (const float*)d_in[3];
  const float* bq = (const float*)d_in[4];
  const float* Wk = (const float*)d_in[5];
  const float* bk = (const float*)d_in[6];
  const float* Wv = (const float*)d_in[7];
  const float* bv = (const float*)d_in[8];
  const float* Wo = (const float*)d_in[9];
  const float* bo = (const float*)d_in[10];

  // ws layout (u16 units):
  u16* Xb  = (u16*)d_ws;               // 25165824 (q|k|v bf16)
  u16* Wb  = Xb + 25165824;            // 4194304  (Wq|Wk|Wv|Wo bf16)
  u16* Qh  = Wb + 4194304;             // 8388608
  u16* Kh  = Qh + 8388608;             // 8388608
  u16* Vt  = Kh + 8388608;             // 8388608   (total ~109 MB)
  u16* ATT = Xb;                        // alias Xb (dead after gemm_qkv)

  float* outO  = (float*)d_out;
  float* attnO = outO + (size_t)8388608;

  cvt_all<<<2048, 256, 0, stream>>>(query, key, value, Wq, Wk, Wv, Wo, Xb, Wb);
  gemm_qkv<<<1536, 256, 0, stream>>>(Xb, Wb, bq, bk, bv, Qh, Kh, Vt);
  attn_fused<<<2048, 256, 0, stream>>>(Qh, Kh, Vt, attnO, ATT);
  gemm_out<<<512, 256, 0, stream>>>(ATT, Wb + 3145728, bo, outO);
}

// Round 17
// 377.010 us; speedup vs baseline: 1.1659x; 1.0053x over previous
//
#include <hip/hip_runtime.h>
#include <hip/hip_bf16.h>

typedef __attribute__((ext_vector_type(8))) short short8;
typedef __attribute__((ext_vector_type(4))) float f32x4;
typedef unsigned short u16;
typedef unsigned int u32;

#define AS1 __attribute__((address_space(1)))
#define AS3 __attribute__((address_space(3)))

__device__ __forceinline__ void cp16(const void* g, void* l) {
  __builtin_amdgcn_global_load_lds((const AS1 u32*)g, (AS3 u32*)l, 16, 0, 0);
}

__device__ __forceinline__ u16 f2bf(float x) {
  union { float f; unsigned u; } c; c.f = x;
  unsigned u = c.u;
  unsigned r = (u + 0x7fffu + ((u >> 16) & 1u)) >> 16;  // RNE
  return (u16)r;
}

// packed pair cvt: compiler emits v_cvt_pk_bf16_f32
__device__ __forceinline__ u32 pk2bf(float a, float b) {
  __hip_bfloat162 h = __float22bfloat162_rn(float2{a, b});
  union { __hip_bfloat162 h; u32 u; } c; c.h = h; return c.u;
}

__device__ __forceinline__ short8 cvt8(float4 x0, float4 x1) {
  short8 v;
  v[0]=(short)f2bf(x0.x); v[1]=(short)f2bf(x0.y); v[2]=(short)f2bf(x0.z); v[3]=(short)f2bf(x0.w);
  v[4]=(short)f2bf(x1.x); v[5]=(short)f2bf(x1.y); v[6]=(short)f2bf(x1.z); v[7]=(short)f2bf(x1.w);
  return v;
}

// -------- convert fp32 -> bf16: query,key,value -> Xb; Wq,Wk,Wv,Wo -> Wb ----
__global__ __launch_bounds__(256) void cvt_all(
    const float* __restrict__ q, const float* __restrict__ k, const float* __restrict__ v,
    const float* __restrict__ wq, const float* __restrict__ wk,
    const float* __restrict__ wv, const float* __restrict__ wo,
    u16* __restrict__ Xb, u16* __restrict__ Wb)
{
  const int TOT = 3670016;                     // chunks of 8 floats
  for (int c = blockIdx.x * 256 + threadIdx.x; c < TOT; c += gridDim.x * 256) {
    const float* s; u16* d;
    if (c < 3145728) {
      int z = c >> 20, off = c & 1048575;
      s = ((z == 0) ? q : (z == 1) ? k : v) + (size_t)off * 8;
      d = Xb + (size_t)c * 8;
    } else {
      int wc = c - 3145728;
      int z = wc >> 17, off = wc & 131071;
      s = ((z == 0) ? wq : (z == 1) ? wk : (z == 2) ? wv : wo) + (size_t)off * 8;
      d = Wb + (size_t)wc * 8;
    }
    float4 a = ((const float4*)s)[0], b = ((const float4*)s)[1];
    *(short8*)d = cvt8(a, b);
  }
}

// -------- bf16 GEMM core: C(128x128) = A(128xK) * B(128xK)^T, K=1024 --------
template<int SWAP>
__device__ __forceinline__ void gemm_core_bf16(const u16* __restrict__ A,
                                               const u16* __restrict__ B,
                                               u16* As, u16* Bs,
                                               f32x4 acc[4][4])
{
  const int tid = threadIdx.x;
  const int lane = tid & 63, wid = tid >> 6;
  const int lo = lane & 15, hi = lane >> 4;
  const int wr0 = (wid >> 1) * 64, wc0 = (wid & 1) * 64;

  for (int k0 = 0; k0 < 1024; k0 += 64) {
    __syncthreads();
#pragma unroll
    for (int it = 0; it < 4; ++it) {
      int idx = it * 256 + tid;            // 1024 chunks of 16B per matrix
      int row = idx >> 3, slot = idx & 7;
      cp16(A + (size_t)row * 1024 + k0 + slot * 8, As + (size_t)idx * 8);
      cp16(B + (size_t)row * 1024 + k0 + slot * 8, Bs + (size_t)idx * 8);
    }
    __syncthreads();
#pragma unroll
    for (int kk = 0; kk < 2; ++kk) {
      short8 af[4], bfr[4];
      int slot = kk * 4 + hi;
#pragma unroll
      for (int i = 0; i < 4; ++i)
        af[i] = *(const short8*)(&As[(wr0 + i * 16 + lo) * 64 + slot * 8]);
#pragma unroll
      for (int j = 0; j < 4; ++j)
        bfr[j] = *(const short8*)(&Bs[(wc0 + j * 16 + lo) * 64 + slot * 8]);
#pragma unroll
      for (int i = 0; i < 4; ++i)
#pragma unroll
        for (int j = 0; j < 4; ++j)
          acc[i][j] = SWAP
            ? __builtin_amdgcn_mfma_f32_16x16x32_bf16(bfr[j], af[i], acc[i][j], 0, 0, 0)
            : __builtin_amdgcn_mfma_f32_16x16x32_bf16(af[i], bfr[j], acc[i][j], 0, 0, 0);
    }
  }
}

// Flat grid 1536, XCD-chunked (A-tile L2 reuse).
// z=0: Q*0.125*log2e -> Qh[bh][s][d]; z=1: K -> Kh; z=2: V -> Vt[bh][d][s]
__global__ __launch_bounds__(256) void gemm_qkv(
    const u16* __restrict__ Xb, const u16* __restrict__ Wb,
    const float* __restrict__ bq, const float* __restrict__ bk, const float* __restrict__ bv,
    u16* __restrict__ Qh, u16* __restrict__ Kh, u16* __restrict__ Vt)
{
  __shared__ __align__(16) u16 As[128 * 64];
  __shared__ __align__(16) u16 Bs[128 * 64];
  const int bid = blockIdx.x;
  const int w = (bid & 7) * 192 + (bid >> 3);
  const int z = w / 512, r = w % 512;
  const int bm0 = (r >> 3) * 128, bn0 = (r & 7) * 128;
  const u16* A = Xb + (size_t)z * 8388608 + (size_t)bm0 * 1024;
  const u16* W = Wb + (size_t)z * 1048576 + (size_t)bn0 * 1024;
  const float* bias = (z == 0) ? bq : (z == 1) ? bk : bv;

  f32x4 acc[4][4] = {};
  if (z < 2) gemm_core_bf16<0>(A, W, As, Bs, acc);
  else       gemm_core_bf16<1>(A, W, As, Bs, acc);

  const int lane = threadIdx.x & 63, wid = threadIdx.x >> 6;
  const int lo = lane & 15, hi = lane >> 4;
  const int wr0 = (wid >> 1) * 64, wc0 = (wid & 1) * 64;

  if (z < 2) {
    u16* out = (z == 0) ? Qh : Kh;
    // Q carries scale AND log2e so softmax runs in base-2 (exp2 only)
    const float sc = (z == 0) ? 0.125f * 1.44269504088896f : 1.0f;
#pragma unroll
    for (int j = 0; j < 4; ++j) {
      int n = bn0 + wc0 + j * 16 + lo;
      float bb = bias[n];
      int h = n >> 6, d = n & 63;
#pragma unroll
      for (int i = 0; i < 4; ++i)
#pragma unroll
        for (int r2 = 0; r2 < 4; ++r2) {
          int m = bm0 + wr0 + i * 16 + hi * 4 + r2;
          int b = m >> 11, s = m & 2047;
          float v = (acc[i][j][r2] + bb) * sc;
          out[(((size_t)(b * 16 + h)) * 2048 + s) * 64 + d] = f2bf(v);
        }
    }
  } else {
#pragma unroll
    for (int j = 0; j < 4; ++j) {
#pragma unroll
      for (int r2 = 0; r2 < 4; ++r2) {
        int n = bn0 + wc0 + j * 16 + hi * 4 + r2;
        float bb = bias[n];
        int h = n >> 6, d = n & 63;
#pragma unroll
        for (int i = 0; i < 4; ++i) {
          int m = bm0 + wr0 + i * 16 + lo;
          int b = m >> 11, s = m & 2047;
          Vt[(((size_t)(b * 16 + h)) * 64 + d) * 2048 + s] = f2bf(acc[i][j][r2] + bb);
        }
      }
    }
  }
}

__global__ __launch_bounds__(256) void gemm_out(
    const u16* __restrict__ ATT, const u16* __restrict__ Wo,
    const float* __restrict__ bo, float* __restrict__ out)
{
  __shared__ __align__(16) u16 As[128 * 64];
  __shared__ __align__(16) u16 Bs[128 * 64];
  const int bid = blockIdx.x;
  const int w = (bid & 7) * 64 + (bid >> 3);
  const int bm0 = (w >> 3) * 128, bn0 = (w & 7) * 128;
  f32x4 acc[4][4] = {};
  gemm_core_bf16<0>(ATT + (size_t)bm0 * 1024, Wo + (size_t)bn0 * 1024, As, Bs, acc);

  const int lane = threadIdx.x & 63, wid = threadIdx.x >> 6;
  const int lo = lane & 15, hi = lane >> 4;
  const int wr0 = (wid >> 1) * 64, wc0 = (wid & 1) * 64;
#pragma unroll
  for (int j = 0; j < 4; ++j) {
    int n = bn0 + wc0 + j * 16 + lo;
    float bb = bo[n];
#pragma unroll
    for (int i = 0; i < 4; ++i)
#pragma unroll
      for (int r = 0; r < 4; ++r) {
        int m = bm0 + wr0 + i * 16 + hi * 4 + r;
        out[(size_t)m * 1024 + n] = acc[i][j][r] + bb;
      }
  }
}

// -------- fused attention: paired pass-1 + T14 + permlane PV + coal. store -
// Block = 64 q-rows of one (b,h); 4 waves x 16 q. KVBLK=64. Base-2 softmax.
// Pass 1: TWO K-tiles per barrier (Ks[b],Vs[b] form 4 K-buffers; Vs is idle
// in pass 1), reg-staged write-late -> 16 barriers. Pass 2 identical to R16:
// K+V reg-dbuf write-late, permlane P-redistribute, LDS-transposed 128B-
// contiguous NT attn stores.
#define C2 11.5415603f   /* 8 * log2(e) */
__global__ __launch_bounds__(256) void attn_fused(
    const u16* __restrict__ Qh, const u16* __restrict__ Kh,
    const u16* __restrict__ Vt, float* __restrict__ attnOut,
    u16* __restrict__ ATT)
{
  __shared__ __align__(16) u16 Ks[2][64 * 64];
  __shared__ __align__(16) u16 Vs[2][64 * 64];
  __shared__ __align__(16) float Tb[4 * 512];   // 8 KB: per-wave 16q x 32t f32
  const int tid = threadIdx.x, lane = tid & 63, wid = tid >> 6;
  const int lo = lane & 15, hi = lane >> 4;
  // XCD swizzle: XCD i owns bh in [i*8, i*8+8)
  const int bid = blockIdx.x;
  const int xcd = bid & 7, idx = bid >> 3;
  const int bh = xcd * 8 + (idx >> 5);
  const int q0 = (idx & 31) * 64;
  const int wq0 = wid * 16;
  const int qr = wq0 + lo;

  const u16* Qg  = Qh + ((size_t)bh * 2048 + q0) * 64;
  const u16* Kg0 = Kh + (size_t)bh * 2048 * 64;
  const u16* Vg0 = Vt + (size_t)bh * 64 * 2048;
  char* Twc = (char*)Tb + wid * 2048;           // this wave's 2 KB slice

  // staging map: thread covers i2 in {tid, 256+tid} -> (row, slot)
  const int srow0 = tid >> 3,         sslot0 = tid & 7;
  const int srow1 = (256 + tid) >> 3, sslot1 = tid & 7;
  const int dst0 = srow0 * 64 + ((sslot0 ^ (srow0 & 7)) << 3);
  const int dst1 = srow1 * 64 + ((sslot1 ^ (srow1 & 7)) << 3);

  short8 qa[2];
#pragma unroll
  for (int kk = 0; kk < 2; ++kk)
    qa[kk] = *(const short8*)(Qg + qr * 64 + (kk * 4 + hi) * 8);

  // ---- pass 1: lsum = sum 2^(sc - C2); paired tiles, 1 barrier / 2 tiles --
  {
    short8 a0 = *(const short8*)(Kg0 + (size_t)srow0 * 64 + sslot0 * 8);
    short8 a1 = *(const short8*)(Kg0 + (size_t)srow1 * 64 + sslot1 * 8);
    short8 b0 = *(const short8*)(Kg0 + 4096 + (size_t)srow0 * 64 + sslot0 * 8);
    short8 b1 = *(const short8*)(Kg0 + 4096 + (size_t)srow1 * 64 + sslot1 * 8);
    *(short8*)(&Ks[0][dst0]) = a0;  *(short8*)(&Ks[0][dst1]) = a1;
    *(short8*)(&Vs[0][dst0]) = b0;  *(short8*)(&Vs[0][dst1]) = b1;
  }
  __syncthreads();
  float lsum = 0.f;
  for (int p = 0; p < 16; ++p) {
    const int cur = p & 1;
    short8 na0, na1, nb0, nb1;
    if (p < 15) {
      const u16* Ka = Kg0 + (size_t)(2 * p + 2) * 4096;
      const u16* Kb = Kg0 + (size_t)(2 * p + 3) * 4096;
      na0 = *(const short8*)(Ka + (size_t)srow0 * 64 + sslot0 * 8);
      na1 = *(const short8*)(Ka + (size_t)srow1 * 64 + sslot1 * 8);
      nb0 = *(const short8*)(Kb + (size_t)srow0 * 64 + sslot0 * 8);
      nb1 = *(const short8*)(Kb + (size_t)srow1 * 64 + sslot1 * 8);
    }
#pragma unroll
    for (int half = 0; half < 2; ++half) {
      const u16* KB = half ? Vs[cur] : Ks[cur];
      f32x4 sc[4] = {};
      __builtin_amdgcn_s_setprio(1);
#pragma unroll
      for (int kk = 0; kk < 2; ++kk) {
        int slot = kk * 4 + hi;
#pragma unroll
        for (int j = 0; j < 4; ++j) {
          int row = j * 16 + lo;
          short8 kb = *(const short8*)(&KB[row * 64 + ((slot ^ (row & 7)) << 3)]);
          sc[j] = __builtin_amdgcn_mfma_f32_16x16x32_bf16(kb, qa[kk], sc[j], 0, 0, 0);
        }
      }
      __builtin_amdgcn_s_setprio(0);
#pragma unroll
      for (int j = 0; j < 4; ++j)
#pragma unroll
        for (int r = 0; r < 4; ++r) lsum += __builtin_amdgcn_exp2f(sc[j][r] - C2);
    }
    if (p < 15) {
      *(short8*)(&Ks[cur ^ 1][dst0]) = na0;  *(short8*)(&Ks[cur ^ 1][dst1]) = na1;
      *(short8*)(&Vs[cur ^ 1][dst0]) = nb0;  *(short8*)(&Vs[cur ^ 1][dst1]) = nb1;
    }
    __syncthreads();
  }
  lsum += __shfl_xor(lsum, 16);
  lsum += __shfl_xor(lsum, 32);
  const float shift2 = C2 + __builtin_amdgcn_logf(lsum);   // p = 2^(sc - shift2)

  // ---- pass 2: K+V reg-dbuf, 1 barrier/tile, permlane PV, coalesced store -
  {
    short8 k0 = *(const short8*)(Kg0 + (size_t)srow0 * 64 + sslot0 * 8);
    short8 k1 = *(const short8*)(Kg0 + (size_t)srow1 * 64 + sslot1 * 8);
    short8 v0 = *(const short8*)(Vg0 + (size_t)srow0 * 2048 + sslot0 * 8);
    short8 v1 = *(const short8*)(Vg0 + (size_t)srow1 * 2048 + sslot1 * 8);
    *(short8*)(&Ks[0][dst0]) = k0;  *(short8*)(&Ks[0][dst1]) = k1;
    *(short8*)(&Vs[0][dst0]) = v0;  *(short8*)(&Vs[0][dst1]) = v1;
  }
  __syncthreads();
  f32x4 oacc[4] = {};
  for (int kt = 0; kt < 32; ++kt) {
    const int cur = kt & 1;
    const int t0 = kt * 64;
    // (1) issue next-tile loads into registers (not drained by s_barrier)
    short8 kn0, kn1, vn0, vn1;
    if (kt < 31) {
      const u16* Kn = Kg0 + (size_t)(kt + 1) * 4096;
      kn0 = *(const short8*)(Kn + (size_t)srow0 * 64 + sslot0 * 8);
      kn1 = *(const short8*)(Kn + (size_t)srow1 * 64 + sslot1 * 8);
      vn0 = *(const short8*)(Vg0 + (size_t)srow0 * 2048 + (t0 + 64) + sslot0 * 8);
      vn1 = *(const short8*)(Vg0 + (size_t)srow1 * 2048 + (t0 + 64) + sslot1 * 8);
    }
    // (2) compute current tile
    f32x4 sc[4] = {};
    __builtin_amdgcn_s_setprio(1);
#pragma unroll
    for (int kk = 0; kk < 2; ++kk) {
      int slot = kk * 4 + hi;
#pragma unroll
      for (int j = 0; j < 4; ++j) {
        int row = j * 16 + lo;
        short8 kb = *(const short8*)(&Ks[cur][row * 64 + ((slot ^ (row & 7)) << 3)]);
        sc[j] = __builtin_amdgcn_mfma_f32_16x16x32_bf16(kb, qa[kk], sc[j], 0, 0, 0);
      }
    }
    __builtin_amdgcn_s_setprio(0);
    float p[4][4];
#pragma unroll
    for (int j = 0; j < 4; ++j)
#pragma unroll
      for (int r = 0; r < 4; ++r) p[j][r] = __builtin_amdgcn_exp2f(sc[j][r] - shift2);

    // T12: P C-layout -> A-layout via permlane (equal-lo lanes only, no LDS).
    u32 w01[4], w23[4];
#pragma unroll
    for (int j = 0; j < 4; ++j) {
      w01[j] = pk2bf(p[j][0], p[j][1]);
      w23[j] = pk2bf(p[j][2], p[j][3]);
    }
#pragma unroll
    for (int c = 0; c < 2; ++c) {
      u32 U = w01[c * 2], V = w01[c * 2 + 1];
      u32 S = w23[c * 2], T = w23[c * 2 + 1];
      asm volatile("v_permlane32_swap_b32 %0, %1" : "+v"(U), "+v"(V));
      asm volatile("v_permlane16_swap_b32 %0, %1" : "+v"(U), "+v"(V));
      asm volatile("v_permlane32_swap_b32 %0, %1" : "+v"(S), "+v"(T));
      asm volatile("v_permlane16_swap_b32 %0, %1" : "+v"(S), "+v"(T));
      short8 pa;
      ((u32*)&pa)[0] = U; ((u32*)&pa)[1] = S;
      ((u32*)&pa)[2] = V; ((u32*)&pa)[3] = T;
      int slot = c * 4 + hi;
      __builtin_amdgcn_s_setprio(1);
#pragma unroll
      for (int j4 = 0; j4 < 4; ++j4) {
        int vrow = j4 * 16 + lo;
        short8 vb = *(const short8*)(&Vs[cur][vrow * 64 + ((slot ^ (vrow & 7)) << 3)]);
        oacc[j4] = __builtin_amdgcn_mfma_f32_16x16x32_bf16(pa, vb, oacc[j4], 0, 0, 0);
      }
      __builtin_amdgcn_s_setprio(0);
    }
    // coalesced attn store: per-wave LDS transpose, two 32-t halves.
#pragma unroll
    for (int c = 0; c < 2; ++c) {
#pragma unroll
      for (int j2 = 0; j2 < 2; ++j2) {
        int j = c * 2 + j2;
        f32x4 f4;
        f4[0] = p[j][0]; f4[1] = p[j][1]; f4[2] = p[j][2]; f4[3] = p[j][3];
        int byte = (lo * 128 + j2 * 64 + hi * 16) ^ ((lo & 7) << 4);
        *(f32x4*)(Twc + byte) = f4;
      }
#pragma unroll
      for (int i2 = 0; i2 < 2; ++i2) {
        int row = i2 * 8 + (lane >> 3), chunk = lane & 7;
        int byte = (row * 128 + chunk * 16) ^ ((row & 7) << 4);
        f32x4 v = *(const f32x4*)(Twc + byte);
        __builtin_nontemporal_store(v,
          (f32x4*)(attnOut + ((size_t)bh * 2048 + q0 + wq0 + row) * 2048
                   + t0 + c * 32 + chunk * 4));
      }
    }
    // (3) write-late: landed regs -> alternate buffer, then ONE barrier
    if (kt < 31) {
      *(short8*)(&Ks[cur ^ 1][dst0]) = kn0;
      *(short8*)(&Ks[cur ^ 1][dst1]) = kn1;
      *(short8*)(&Vs[cur ^ 1][dst0]) = vn0;
      *(short8*)(&Vs[cur ^ 1][dst1]) = vn1;
    }
    __syncthreads();
  }
  // attended -> ATT[b*2048+q][h*64+d] bf16 (col=lo -> d, row=hi*4+r -> q)
  const int b = bh >> 4, h = bh & 15;
#pragma unroll
  for (int j = 0; j < 4; ++j)
#pragma unroll
    for (int r = 0; r < 4; ++r) {
      int ql = wq0 + hi * 4 + r;
      int d = j * 16 + lo;
      size_t row = (size_t)b * 2048 + q0 + ql;
      ATT[row * 1024 + h * 64 + d] = f2bf(oacc[j][r]);
    }
}

extern "C" void kernel_launch(void* const* d_in, const int* in_sizes, int n_in,
                              void* d_out, int out_size, void* d_ws, size_t ws_size,
                              hipStream_t stream) {
  const float* query = (const float*)d_in[0];
  const float* key   = (const float*)d_in[1];
  const float* value = (const float*)d_in[2];
  const float* Wq = (const float*)d_in[3];
  const float* bq = (const float*)d_in[4];
  const float* Wk = (const float*)d_in[5];
  const float* bk = (const float*)d_in[6];
  const float* Wv = (const float*)d_in[7];
  const float* bv = (const float*)d_in[8];
  const float* Wo = (const float*)d_in[9];
  const float* bo = (const float*)d_in[10];

  // ws layout (u16 units):
  u16* Xb  = (u16*)d_ws;               // 25165824 (q|k|v bf16)
  u16* Wb  = Xb + 25165824;            // 4194304  (Wq|Wk|Wv|Wo bf16)
  u16* Qh  = Wb + 4194304;             // 8388608
  u16* Kh  = Qh + 8388608;             // 8388608
  u16* Vt  = Kh + 8388608;             // 8388608   (total ~109 MB)
  u16* ATT = Xb;                        // alias Xb (dead after gemm_qkv)

  float* outO  = (float*)d_out;
  float* attnO = outO + (size_t)8388608;

  cvt_all<<<2048, 256, 0, stream>>>(query, key, value, Wq, Wk, Wv, Wo, Xb, Wb);
  gemm_qkv<<<1536, 256, 0, stream>>>(Xb, Wb, bq, bk, bv, Qh, Kh, Vt);
  attn_fused<<<2048, 256, 0, stream>>>(Qh, Kh, Vt, attnO, ATT);
  gemm_out<<<512, 256, 0, stream>>>(ATT, Wb + 3145728, bo, outO);
}